// Round 5
// baseline (592.174 us; speedup 1.0000x reference)
//
#include <hip/hip_runtime.h>

#define T_STEPS 512
#define BATCH   64
#define HID     64
#define G3      192      // 3*HID
#define DIN     2048
#define B_BLK   16
#define NBLK    4        // BATCH / B_BLK

typedef float  f32x4  __attribute__((ext_vector_type(4)));
typedef short  short8 __attribute__((ext_vector_type(8)));

__device__ __forceinline__ unsigned short f2bf(float f) {
    unsigned int u = __builtin_bit_cast(unsigned int, f);
    unsigned int r = u + 0x7fffu + ((u >> 16) & 1u);   // RNE
    return (unsigned short)(r >> 16);
}
// HW packed f32->bf16 (RNE), 1 instruction
__device__ __forceinline__ unsigned int cvtpk(float a, float b) {
    unsigned int r;
    asm("v_cvt_pk_bf16_f32 %0, %1, %2" : "=v"(r) : "v"(a), "v"(b));
    return r;
}
__device__ __forceinline__ float bflo(unsigned int u) {
    return __builtin_bit_cast(float, u << 16);
}
__device__ __forceinline__ float bfhi(unsigned int u) {
    return __builtin_bit_cast(float, u & 0xffff0000u);
}
// barrier WITHOUT vmcnt drain: orders LDS (lgkmcnt) only; keeps global
// prefetch loads in flight across the barrier.
__device__ __forceinline__ void wg_barrier() {
    asm volatile("s_waitcnt lgkmcnt(0)" ::: "memory");
    __builtin_amdgcn_s_barrier();
    asm volatile("" ::: "memory");
}

// ---------------- Kernel 1: xi = x @ W_ih0^T + b_ih0  (bf16 MFMA) ----------
// Output: bf16, layout xi[t][b][g], g = gate*64 + row.
#define BM  128
#define BK  64
#define LDA 72
#define LDB 72

__launch_bounds__(512, 1)
__global__ void proj0_kernel(const float* __restrict__ x,
                             const float* __restrict__ Wih0,
                             const float* __restrict__ bih0,
                             unsigned short* __restrict__ xi)
{
    __shared__ unsigned short Asm[BM * LDA];
    __shared__ unsigned short Bsm[G3 * LDB];

    const int tid  = threadIdx.x;
    const int wave = tid >> 6;
    const int lane = tid & 63;
    const int wm   = wave >> 2;
    const int wn   = wave & 3;
    const int m0   = blockIdx.x * BM;
    const int l16  = lane & 15;
    const int lk   = lane >> 4;
    const int rA   = tid >> 4;       // 0..31
    const int c4   = tid & 15;

    const float* xb = x    + (size_t)(m0 + rA) * DIN + c4 * 4;
    const float* wb = Wih0 + (size_t)rA        * DIN + c4 * 4;
    unsigned short* ap = Asm + rA * LDA + c4 * 4;
    unsigned short* bp = Bsm + rA * LDB + c4 * 4;

    f32x4 acc[4][3];
#pragma unroll
    for (int mi = 0; mi < 4; ++mi)
#pragma unroll
        for (int ni = 0; ni < 3; ++ni)
            acc[mi][ni] = (f32x4){0.f, 0.f, 0.f, 0.f};

    float4 stA[4], stB[6];
#pragma unroll
    for (int it = 0; it < 4; ++it) stA[it] = *(const float4*)(xb + it * 32 * DIN);
#pragma unroll
    for (int it = 0; it < 6; ++it) stB[it] = *(const float4*)(wb + it * 32 * DIN);

    for (int kt = 0; kt < DIN / BK; ++kt) {
#pragma unroll
        for (int it = 0; it < 4; ++it) {
            uint2 pk;
            pk.x = cvtpk(stA[it].x, stA[it].y);
            pk.y = cvtpk(stA[it].z, stA[it].w);
            *(uint2*)(ap + it * 32 * LDA) = pk;
        }
#pragma unroll
        for (int it = 0; it < 6; ++it) {
            uint2 pk;
            pk.x = cvtpk(stB[it].x, stB[it].y);
            pk.y = cvtpk(stB[it].z, stB[it].w);
            *(uint2*)(bp + it * 32 * LDB) = pk;
        }
        if (kt + 1 < DIN / BK) {
            const int kk = (kt + 1) * BK;
#pragma unroll
            for (int it = 0; it < 4; ++it) stA[it] = *(const float4*)(xb + kk + it * 32 * DIN);
#pragma unroll
            for (int it = 0; it < 6; ++it) stB[it] = *(const float4*)(wb + kk + it * 32 * DIN);
        }
        wg_barrier();

#pragma unroll
        for (int ks = 0; ks < 2; ++ks) {
            const int kb = ks * 32 + lk * 8;
            short8 a[4], bfr[3];
#pragma unroll
            for (int mi = 0; mi < 4; ++mi)
                a[mi] = *(const short8*)&Asm[(wm * 64 + mi * 16 + l16) * LDA + kb];
#pragma unroll
            for (int ni = 0; ni < 3; ++ni)
                bfr[ni] = *(const short8*)&Bsm[(wn * 48 + ni * 16 + l16) * LDB + kb];
#pragma unroll
            for (int mi = 0; mi < 4; ++mi)
#pragma unroll
                for (int ni = 0; ni < 3; ++ni)
                    acc[mi][ni] = __builtin_amdgcn_mfma_f32_16x16x32_bf16(
                        a[mi], bfr[ni], acc[mi][ni], 0, 0, 0);
        }
        wg_barrier();
    }

#pragma unroll
    for (int ni = 0; ni < 3; ++ni) {
        int g = wn * 48 + ni * 16 + l16;      // = gate*64 + row
        float bias = bih0[g];
#pragma unroll
        for (int mi = 0; mi < 4; ++mi) {
#pragma unroll
            for (int r = 0; r < 4; ++r) {
                int m  = m0 + wm * 64 + mi * 16 + lk * 4 + r;
                int t  = m & 511;
                int bb = m >> 9;
                xi[(size_t)(t * BATCH + bb) * G3 + g] = f2bf(acc[mi][ni][r] + bias);
            }
        }
    }
}

// ---------------- Kernel 2: MFMA-batched fused 2-layer GRU + FC ------------
// 4 blocks x 16 batch x 4 waves (256 thr). Each wave owns hidden rows
// 16w..16w+15 of BOTH layers: 6 MFMA (L0) + 12 MFMA (L1, one step behind)
// + 8 gate units/lane, interleaved in ONE instruction stream so the two
// dependency chains hide each other's latency. ONE lgkm-only barrier/step.
// Gates use the PQ rcp-merge: 5 trans ops per unit instead of 6.
__launch_bounds__(256, 1)
__global__ void gru_fused_kernel(const unsigned short* __restrict__ xi,
                                 const float* __restrict__ Whh0,
                                 const float* __restrict__ bhh0,
                                 const float* __restrict__ Wih1,
                                 const float* __restrict__ bih1,
                                 const float* __restrict__ Whh1,
                                 const float* __restrict__ bhh1,
                                 const float* __restrict__ fcw,
                                 const float* __restrict__ fcb,
                                 float* __restrict__ out)
{
    __shared__ __align__(16) unsigned short h0d[2][8][B_BLK][8];  // 4 KB
    __shared__ __align__(16) unsigned short h1d[2][8][B_BLK][8];  // 4 KB
    __shared__ float fcbuf[B_BLK][68];

    const int tid = threadIdx.x;
    const int w   = tid >> 6;        // wave 0..3
    const int l   = tid & 63;
    const int c   = l & 15;          // batch-in-block / MFMA col / A-row
    const int kg  = l >> 4;          // 0..3
    const int blk = blockIdx.x;
    const int jw  = w * 16;          // hidden-row base owned by this wave

    // ---- stationary weight fragments (A-operand) + bias regs ----
    short8 fragA[6], fragI[6], fragH[6];   // Whh0, Wih1, Whh1
    f32x4  bA[3], bI[3], bH[3];
#pragma unroll
    for (int g = 0; g < 3; ++g) {
#pragma unroll
        for (int ks = 0; ks < 2; ++ks) {
            const size_t roff = (size_t)(g * 64 + jw + c) * HID + ks * 32 + kg * 8;
            short8 s;
#pragma unroll
            for (int j = 0; j < 8; ++j) s[j] = (short)f2bf(Whh0[roff + j]);
            fragA[g * 2 + ks] = s;
#pragma unroll
            for (int j = 0; j < 8; ++j) s[j] = (short)f2bf(Wih1[roff + j]);
            fragI[g * 2 + ks] = s;
#pragma unroll
            for (int j = 0; j < 8; ++j) s[j] = (short)f2bf(Whh1[roff + j]);
            fragH[g * 2 + ks] = s;
        }
        float4 va = *(const float4*)&bhh0[g * 64 + jw + kg * 4];
        float4 vi = *(const float4*)&bih1[g * 64 + jw + kg * 4];
        float4 vh = *(const float4*)&bhh1[g * 64 + jw + kg * 4];
        bA[g] = (f32x4){va.x, va.y, va.z, va.w};
        bI[g] = (f32x4){vi.x, vi.y, vi.z, vi.w};
        bH[g] = (f32x4){vh.x, vh.y, vh.z, vh.w};
    }

    float h0r[4] = {0.f, 0.f, 0.f, 0.f};
    float h1r[4] = {0.f, 0.f, 0.f, 0.f};

    // zero h buffers (1024 uints each)
    for (int i = tid; i < 1024; i += 256) {
        ((unsigned int*)h0d)[i] = 0;
        ((unsigned int*)h1d)[i] = 0;
    }

    // xi prefetch base + prologue loads, depth 2
    const unsigned short* xp =
        xi + (size_t)(blk * B_BLK + c) * G3 + jw + kg * 4;
    uint2 pA[3], pB[3];
    pA[0] = *(const uint2*)(xp);
    pA[1] = *(const uint2*)(xp + 64);
    pA[2] = *(const uint2*)(xp + 128);
    {
        const unsigned short* p1 = xp + (size_t)BATCH * G3;
        pB[0] = *(const uint2*)(p1);
        pB[1] = *(const uint2*)(p1 + 64);
        pB[2] = *(const uint2*)(p1 + 128);
    }
    __syncthreads();

    const int chunk = 2 * w + (kg >> 1);
    const int coff  = (kg & 1) * 4;

    auto gru_step = [&](int t, uint2 (&cur)[3]) {
        const int pb = (t + 1) & 1;                    // h0(t-1) buffer
        short8 x0 = *(const short8*)&h0d[pb][kg][c][0];
        short8 x1 = *(const short8*)&h0d[pb][4 + kg][c][0];

        // ---- L0: h0(t) ----
        if (t < T_STEPS) {
            f32x4 a0 = bA[0], a1 = bA[1], a2 = bA[2];
            a0 = __builtin_amdgcn_mfma_f32_16x16x32_bf16(fragA[0], x0, a0, 0, 0, 0);
            a0 = __builtin_amdgcn_mfma_f32_16x16x32_bf16(fragA[1], x1, a0, 0, 0, 0);
            a1 = __builtin_amdgcn_mfma_f32_16x16x32_bf16(fragA[2], x0, a1, 0, 0, 0);
            a1 = __builtin_amdgcn_mfma_f32_16x16x32_bf16(fragA[3], x1, a1, 0, 0, 0);
            a2 = __builtin_amdgcn_mfma_f32_16x16x32_bf16(fragA[4], x0, a2, 0, 0, 0);
            a2 = __builtin_amdgcn_mfma_f32_16x16x32_bf16(fragA[5], x1, a2, 0, 0, 0);

            float xrf[4] = {bflo(cur[0].x), bfhi(cur[0].x), bflo(cur[0].y), bfhi(cur[0].y)};
            float xzf[4] = {bflo(cur[1].x), bfhi(cur[1].x), bflo(cur[1].y), bfhi(cur[1].y)};
            float xnf[4] = {bflo(cur[2].x), bfhi(cur[2].x), bflo(cur[2].y), bfhi(cur[2].y)};
            if (t + 2 < T_STEPS) {
                const unsigned short* p = xp + (size_t)(t + 2) * (BATCH * G3);
                cur[0] = *(const uint2*)(p);
                cur[1] = *(const uint2*)(p + 64);
                cur[2] = *(const uint2*)(p + 128);
            }
#pragma unroll
            for (int q = 0; q < 4; ++q) {
                float gr = xrf[q] + a0[q];
                float gz = xzf[q] + a1[q];
                float R  = 1.f + __expf(-gr);
                float r  = __builtin_amdgcn_rcpf(R);
                float Q  = 1.f + __expf(-gz);
                float s  = fmaf(r, a2[q], xnf[q]);
                float P  = 1.f + __expf(s + s);
                float ipq = __builtin_amdgcn_rcpf(P * Q);
                float n  = fmaf(-2.f, ipq * Q, 1.f);   // tanh(s)
                h0r[q]   = fmaf(h0r[q] - n, ipq * P, n); // n + z*(h-n)
            }
            uint2 hw;
            hw.x = cvtpk(h0r[0], h0r[1]);
            hw.y = cvtpk(h0r[2], h0r[3]);
            *(uint2*)&h0d[t & 1][chunk][c][coff] = hw;
        }

        // ---- L1: h1(t-1) ----
        if (t >= 1 && t <= T_STEPS) {
            const int p1 = t & 1;                      // h1(t-2) buffer
            short8 y0 = *(const short8*)&h1d[p1][kg][c][0];
            short8 y1 = *(const short8*)&h1d[p1][4 + kg][c][0];
            f32x4 i0 = bI[0], i1 = bI[1], i2 = bI[2];
            f32x4 g0 = bH[0], g1 = bH[1], g2 = bH[2];
            i0 = __builtin_amdgcn_mfma_f32_16x16x32_bf16(fragI[0], x0, i0, 0, 0, 0);
            i0 = __builtin_amdgcn_mfma_f32_16x16x32_bf16(fragI[1], x1, i0, 0, 0, 0);
            i1 = __builtin_amdgcn_mfma_f32_16x16x32_bf16(fragI[2], x0, i1, 0, 0, 0);
            i1 = __builtin_amdgcn_mfma_f32_16x16x32_bf16(fragI[3], x1, i1, 0, 0, 0);
            i2 = __builtin_amdgcn_mfma_f32_16x16x32_bf16(fragI[4], x0, i2, 0, 0, 0);
            i2 = __builtin_amdgcn_mfma_f32_16x16x32_bf16(fragI[5], x1, i2, 0, 0, 0);
            g0 = __builtin_amdgcn_mfma_f32_16x16x32_bf16(fragH[0], y0, g0, 0, 0, 0);
            g0 = __builtin_amdgcn_mfma_f32_16x16x32_bf16(fragH[1], y1, g0, 0, 0, 0);
            g1 = __builtin_amdgcn_mfma_f32_16x16x32_bf16(fragH[2], y0, g1, 0, 0, 0);
            g1 = __builtin_amdgcn_mfma_f32_16x16x32_bf16(fragH[3], y1, g1, 0, 0, 0);
            g2 = __builtin_amdgcn_mfma_f32_16x16x32_bf16(fragH[4], y0, g2, 0, 0, 0);
            g2 = __builtin_amdgcn_mfma_f32_16x16x32_bf16(fragH[5], y1, g2, 0, 0, 0);
#pragma unroll
            for (int q = 0; q < 4; ++q) {
                float gr = i0[q] + g0[q];
                float gz = i1[q] + g1[q];
                float R  = 1.f + __expf(-gr);
                float r  = __builtin_amdgcn_rcpf(R);
                float Q  = 1.f + __expf(-gz);
                float s  = fmaf(r, g2[q], i2[q]);
                float P  = 1.f + __expf(s + s);
                float ipq = __builtin_amdgcn_rcpf(P * Q);
                float n  = fmaf(-2.f, ipq * Q, 1.f);
                h1r[q]   = fmaf(h1r[q] - n, ipq * P, n);
            }
            uint2 hw;
            hw.x = cvtpk(h1r[0], h1r[1]);
            hw.y = cvtpk(h1r[2], h1r[3]);
            *(uint2*)&h1d[(t + 1) & 1][chunk][c][coff] = hw;   // h1(t-1)
        }
        wg_barrier();
    };

    for (int tt = 0; tt < T_STEPS + 2; tt += 2) {   // t = 0..513
        gru_step(tt, pA);
        gru_step(tt + 1, pB);
    }

    // ---- FC: out[b] = h1(511) . fc_w + fc_b ----
#pragma unroll
    for (int q = 0; q < 4; ++q)
        fcbuf[c][jw + kg * 4 + q] = h1r[q];
    __syncthreads();
    if (w == 0) {
        float p = 0.f;
#pragma unroll
        for (int jj = 0; jj < 16; ++jj)
            p += fcbuf[c][kg * 16 + jj] * fcw[kg * 16 + jj];
        p += __shfl_xor(p, 16);
        p += __shfl_xor(p, 32);
        if (kg == 0) out[blk * B_BLK + c] = p + fcb[0];
    }
}

extern "C" void kernel_launch(void* const* d_in, const int* in_sizes, int n_in,
                              void* d_out, int out_size, void* d_ws, size_t ws_size,
                              hipStream_t stream)
{
    const float* x    = (const float*)d_in[0];
    const float* Wih0 = (const float*)d_in[1];
    const float* Whh0 = (const float*)d_in[2];
    const float* bih0 = (const float*)d_in[3];
    const float* bhh0 = (const float*)d_in[4];
    const float* Wih1 = (const float*)d_in[5];
    const float* Whh1 = (const float*)d_in[6];
    const float* bih1 = (const float*)d_in[7];
    const float* bhh1 = (const float*)d_in[8];
    const float* fcw  = (const float*)d_in[9];
    const float* fcb  = (const float*)d_in[10];
    float* out = (float*)d_out;
    unsigned short* xi = (unsigned short*)d_ws;   // 512*64*192 bf16 = 12.6 MB

    hipLaunchKernelGGL(proj0_kernel, dim3(32768 / BM), dim3(512), 0, stream,
                       x, Wih0, bih0, xi);
    hipLaunchKernelGGL(gru_fused_kernel, dim3(NBLK), dim3(256), 0, stream,
                       xi, Whh0, bhh0, Wih1, bih1, Whh1, bhh1, fcw, fcb, out);
}